// Round 7
// baseline (79.075 us; speedup 1.0000x reference)
//
#include <hip/hip_runtime.h>

#define NRES  300
#define NTRJ  20
#define NBINS 34
#define PLANE (NTRJ * NRES * 3)      // 18000 floats per output tensor
#define NJT   5                      // j-tiles of 64 lanes
#define IC    3                      // i's per block
#define NCH   100                    // 300 / IC
#define NB    5                      // trajectories per lane (register-blocked)
#define TILEF (64 * NBINS)           // 2176 floats per staged gw row
#define TILE4 (TILEF / 4)            // 544 float4
#define PART_FLOATS (2ull * NCH * PLANE)   // CB + O partials: 14.4 MB

__device__ __forceinline__ float red64(float v) {
#pragma unroll
  for (int m = 1; m < 64; m <<= 1) v += __shfl_xor(v, m, 64);
  return v;
}

// Block = (j-tile of 64, i-chunk of 3) x ALL 20 trajectories (4 waves x NB=5).
// gw row (i, j-tile) is coalesced-loaded ONCE from HBM (float4), staged in
// double-buffered LDS (register prefetch hides latency), then each lane pulls
// its 34 weights via 2-way-aliased ds_read_b64 (free) and reuses them across
// 5 trajectories in registers. CB/O accumulate in registers -> plain stores
// of per-chunk partials to ws; accs_H via 64-lane reduce + lane-0 atomic.
template <bool PART>
__global__ __launch_bounds__(256, 4)
void force_kernel(const float* __restrict__ cO,
                  const float* __restrict__ cCB,
                  const float* __restrict__ cH,
                  const float* __restrict__ gw,
                  const float* __restrict__ hmin,
                  const float* __restrict__ hmax,
                  float* __restrict__ out,
                  float* __restrict__ part) {
  __shared__ float wlds[2][TILEF];
  __shared__ float sCB[NTRJ * IC * 3];   // i-side CB coords for the chunk
  __shared__ float sHH[NTRJ * IC * 3];   // i-side H coords

  float* accO  = out + 2 * PLANE;
  float* accCB = out + 3 * PLANE;
  float* accH  = out + 4 * PLANE;

  const int tid  = threadIdx.x;
  const int wv   = tid >> 6;
  const int lane = tid & 63;
  const int b0   = wv * NB;            // wave's 5 trajectories
  const int bx   = blockIdx.x;
  const int jt   = bx % NJT;
  const int ch   = bx / NJT;           // 0..NCH-1
  const int i0   = ch * IC;
  const int j    = jt * 64 + lane;
  const bool jv  = (j < NRES);
  const int jc   = jv ? j : NRES - 1;
  const int F4   = (jt == 4) ? ((NRES - 256) * NBINS) / 4 : TILE4; // valid f4/row

  // stage i-side coords for the whole chunk (20 b x IC i x 3)
  if (tid < NTRJ * IC * 3) {
    const int b  = tid / (IC * 3);
    const int r  = tid % (IC * 3);
    const int ii = r / 3, c = r % 3;
    sCB[tid] = cCB[((b * NRES) + i0 + ii) * 3 + c];
    sHH[tid] = cH [((b * NRES) + i0 + ii) * 3 + c];
  }

  // this lane's j-side coordinates for its 5 trajectories (fixed all kernel)
  float pjx[NB], pjy[NB], pjz[NB], pox[NB], poy[NB], poz[NB];
  float acx[NB] = {}, acy[NB] = {}, acz[NB] = {};   // accs_CB[b,j]
  float aox[NB] = {}, aoy[NB] = {}, aoz[NB] = {};   // accs_O [b,j]
#pragma unroll
  for (int q = 0; q < NB; ++q) {
    const float* p = cCB + ((size_t)((b0 + q) * NRES + jc)) * 3;
    pjx[q] = p[0]; pjy[q] = p[1]; pjz[q] = p[2];
    const float* o = cO + ((size_t)((b0 + q) * NRES + jc)) * 3;
    pox[q] = o[0]; poy[q] = o[1]; poz[q] = o[2];
  }

  // prefetch first gw row (coalesced float4; rows are 16B-aligned)
  float4 r4[3];
  {
    const float4* src = (const float4*)(gw + ((size_t)i0 * NRES + jt * 64) * NBINS);
#pragma unroll
    for (int q = 0; q < 3; ++q) {
      const int e = tid + q * 256;
      r4[q] = (e < F4) ? src[e] : make_float4(0.f, 0.f, 0.f, 0.f);
    }
  }

  int p = 0;
  for (int ii = 0; ii < IC; ++ii) {
    const int i = i0 + ii;

    // write staged row (zero-padded tail on jt==4), then one barrier
    float4* dst = (float4*)wlds[p];
#pragma unroll
    for (int q = 0; q < 3; ++q) {
      const int e = tid + q * 256;
      if (e < TILE4) dst[e] = r4[q];
    }
    __syncthreads();

    // issue next row's loads early; HBM latency hides under the 5-b compute
    if (ii + 1 < IC) {
      const float4* src =
          (const float4*)(gw + ((size_t)(i + 1) * NRES + jt * 64) * NBINS);
#pragma unroll
      for (int q = 0; q < 3; ++q) {
        const int e = tid + q * 256;
        r4[q] = (e < F4) ? src[e] : make_float4(0.f, 0.f, 0.f, 0.f);
      }
    }

    // my j's weight row from LDS (2-way bank aliasing = free)
    float w[36];
    const float2* p2 = (const float2*)(wlds[p] + lane * NBINS);
#pragma unroll
    for (int k = 0; k < 17; ++k) { float2 v = p2[k]; w[2*k] = v.x; w[2*k+1] = v.y; }
    w[34] = 0.f; w[35] = 0.f;

    const float hmn = hmin[i * NRES + jc];
    const float hmx = hmax[i * NRES + jc];

#pragma unroll
    for (int q = 0; q < NB; ++q) {
      const int b = b0 + q;
      const float* pi = &sCB[((b * IC) + ii) * 3];
      const float* ph = &sHH[((b * IC) + ii) * 3];

      // ---- CB distogram force: 3 x 12-bin gaussian recurrence ----
      float dx = pjx[q] - pi[0], dy = pjy[q] - pi[1], dz = pjz[q] - pi[2];
      float d2 = fmaf(dx, dx, fmaf(dy, dy, dz * dz));
      d2 = fminf(fmaxf(d2, 0.01f), 1600.0f);      // d in [0.1, 40]
      float rinv = __frsqrt_rn(d2);
      float d    = d2 * rinv;

      float dA = d - 3.75f, dB = d - 9.75f, dC = d - 15.75f;
      float gA = __expf(-0.32f * dA * dA), mA = __expf(fmaf(0.32f, dA, -0.08f));
      float gB = __expf(-0.32f * dB * dB), mB = __expf(fmaf(0.32f, dB, -0.08f));
      float gC = __expf(-0.32f * dC * dC), mC = __expf(fmaf(0.32f, dC, -0.08f));
      float s0 = 0.f, s1 = 0.f, s2 = 0.f;
#pragma unroll
      for (int k = 0; k < 12; ++k) {
        s0 = fmaf(w[k]      * dA, gA, s0); gA *= mA; mA *= 0.85214379f; dA -= 0.5f;
        s1 = fmaf(w[k + 12] * dB, gB, s1); gB *= mB; mB *= 0.85214379f; dB -= 0.5f;
        s2 = fmaf(w[k + 24] * dC, gC, s2); gC *= mC; mC *= 0.85214379f; dC -= 0.5f;
      }
      float cf = 76.8f * ((s0 + s1) + s2) * rinv;  // 150 / sigma^3
      acx[q] = fmaf(cf, dx, acx[q]);
      acy[q] = fmaf(cf, dy, acy[q]);
      acz[q] = fmaf(cf, dz, acz[q]);

      // ---- HB min/max restraint (O_j - H_i) ----
      float ex = pox[q] - ph[0], ey = poy[q] - ph[1], ez = poz[q] - ph[2];
      float e2 = fmaf(ex, ex, fmaf(ey, ey, ez * ez));
      e2 = fminf(fmaxf(e2, 0.01f), 1600.0f);
      float rh = __frsqrt_rn(e2);
      float dh = e2 * rh;
      float vmin = fmaxf(hmn - dh, 0.0f);
      float vmax = fmaxf(dh - hmx, 0.0f);
      float fmn = 15.0f * vmin;                    // 3*5*v^1
      float fmx = (vmax > 0.0f) ? 5.0f * __powf(vmax, 0.75f) : 0.0f;
      float ff = (fmn - fmx) * rh;
      aox[q] = fmaf(ff, ex, aox[q]);
      aoy[q] = fmaf(ff, ey, aoy[q]);
      aoz[q] = fmaf(ff, ez, aoz[q]);

      // ---- accs_H[b,i] = -sum_j pair_hb : 64-lane reduce, 1 atomic ----
      float qx = jv ? ff * ex : 0.f;
      float qy = jv ? ff * ey : 0.f;
      float qz = jv ? ff * ez : 0.f;
      qx = red64(qx); qy = red64(qy); qz = red64(qz);
      if (lane == 0) {
        const int hb = (b * NRES + i) * 3;
        atomicAdd(&accH[hb + 0], -qx);
        atomicAdd(&accH[hb + 1], -qy);
        atomicAdd(&accH[hb + 2], -qz);
      }
    }
    p ^= 1;
  }

  if (jv) {
    if constexpr (PART) {
      float* pc  = part + (size_t)ch * PLANE;
      float* po2 = part + (size_t)(NCH + ch) * PLANE;
#pragma unroll
      for (int q = 0; q < NB; ++q) {
        const int base = ((b0 + q) * NRES + j) * 3;
        pc[base + 0]  = acx[q]; pc[base + 1]  = acy[q]; pc[base + 2]  = acz[q];
        po2[base + 0] = aox[q]; po2[base + 1] = aoy[q]; po2[base + 2] = aoz[q];
      }
    } else {
#pragma unroll
      for (int q = 0; q < NB; ++q) {
        const int base = ((b0 + q) * NRES + j) * 3;
        atomicAdd(&accCB[base + 0], acx[q]);
        atomicAdd(&accCB[base + 1], acy[q]);
        atomicAdd(&accCB[base + 2], acz[q]);
        atomicAdd(&accO[base + 0], aox[q]);
        atomicAdd(&accO[base + 1], aoy[q]);
        atomicAdd(&accO[base + 2], aoz[q]);
      }
    }
  }
}

// out[t] = sum over NCH chunk planes (coalesced stride-PLANE reads)
__global__ __launch_bounds__(256)
void reduce_part(const float* __restrict__ part, float* __restrict__ out) {
  const int t = blockIdx.x * 256 + threadIdx.x;
  if (t >= PLANE) return;
  float scb = 0.f, so = 0.f;
  const float* pc = part + t;
  const float* po = part + (size_t)NCH * PLANE + t;
#pragma unroll 4
  for (int ch = 0; ch < NCH; ++ch) {
    scb += pc[(size_t)ch * PLANE];
    so  += po[(size_t)ch * PLANE];
  }
  out[3 * PLANE + t] = scb;   // accs_CB
  out[2 * PLANE + t] = so;    // accs_O
}

extern "C" void kernel_launch(void* const* d_in, const int* in_sizes, int n_in,
                              void* d_out, int out_size, void* d_ws, size_t ws_size,
                              hipStream_t stream) {
  // input order per setup_inputs(): N, C, O, CB, H, gaussian_weights, hb_min, hb_max
  const float* cO  = (const float*)d_in[2];
  const float* cCB = (const float*)d_in[3];
  const float* cH  = (const float*)d_in[4];
  const float* gw  = (const float*)d_in[5];
  const float* hmn = (const float*)d_in[6];
  const float* hmx = (const float*)d_in[7];
  float* out = (float*)d_out;

  // accs_N and accs_C are exactly zero (K_ANG_HB_GEN == 0); H atomics need a
  // zeroed plane -> zero the whole output every call (deterministic).
  hipMemsetAsync(out, 0, (size_t)out_size * sizeof(float), stream);

  if (ws_size >= PART_FLOATS * sizeof(float)) {
    float* part = (float*)d_ws;
    force_kernel<true><<<dim3(NJT * NCH), dim3(256), 0, stream>>>(
        cO, cCB, cH, gw, hmn, hmx, out, part);
    reduce_part<<<dim3((PLANE + 255) / 256), dim3(256), 0, stream>>>(part, out);
  } else {
    force_kernel<false><<<dim3(NJT * NCH), dim3(256), 0, stream>>>(
        cO, cCB, cH, gw, hmn, hmx, out, nullptr);
  }
}